// Round 3
// baseline (630.687 us; speedup 1.0000x reference)
//
#include <hip/hip_runtime.h>

// FeatureGrid: trilinear interp of N points into (C=32, 128^3) f32 grid.
// R3: R2 with native ext_vector float4 for nontemporal builtins (HIP float4
// is a class type the builtin rejects).

constexpr int   GD      = 128;
constexpr long long SPATIAL = (long long)GD * GD * GD; // 2097152
constexpr int   FD      = 32;
constexpr float PLO     = -10.0f;
constexpr float PHI     = 10.0f;
constexpr int   NBUCKET = 32 * 32 * 32; // 4^3-cell buckets

typedef float vf4 __attribute__((ext_vector_type(4)));  // native vec for NT builtins

// ---------------- transpose (C, S) -> (S, C), float4 both sides ----------
__global__ __launch_bounds__(256) void transpose_feat_v4(
    const float* __restrict__ f, float* __restrict__ o) {
    __shared__ float lds[64][FD + 1];
    const int t  = threadIdx.x;
    const int s0 = blockIdx.x * 64;
    const int sq = t & 15;
    const int cg = t >> 4;  // 0..15
#pragma unroll
    for (int rep = 0; rep < 2; ++rep) {
        const int c = cg + rep * 16;
        const vf4 v = __builtin_nontemporal_load(
            reinterpret_cast<const vf4*>(f + (size_t)c * SPATIAL + s0 + sq * 4));
        lds[sq * 4 + 0][c] = v.x;
        lds[sq * 4 + 1][c] = v.y;
        lds[sq * 4 + 2][c] = v.z;
        lds[sq * 4 + 3][c] = v.w;
    }
    __syncthreads();
    const int cq = t & 7;
    const int sw = t >> 3;  // 0..31
#pragma unroll
    for (int rep = 0; rep < 2; ++rep) {
        const int s = sw + rep * 32;
        vf4 w;
        w.x = lds[s][cq * 4 + 0];
        w.y = lds[s][cq * 4 + 1];
        w.z = lds[s][cq * 4 + 2];
        w.w = lds[s][cq * 4 + 3];
        *reinterpret_cast<vf4*>(o + (size_t)(s0 + s) * FD + cq * 4) = w;
    }
}

__device__ __forceinline__ void cell_of(float px, float py, float pz,
                                        int& x0, int& y0, int& z0) {
    const float cx = 2.0f * (px - PLO) / (PHI - PLO) - 1.0f;
    const float cy = 2.0f * (py - PLO) / (PHI - PLO) - 1.0f;
    const float cz = 2.0f * (pz - PLO) / (PHI - PLO) - 1.0f;
    const float fx = ((cx + 1.0f) * GD - 1.0f) * 0.5f;
    const float fy = ((cy + 1.0f) * GD - 1.0f) * 0.5f;
    const float fz = ((cz + 1.0f) * GD - 1.0f) * 0.5f;
    x0 = (int)floorf(fx);
    y0 = (int)floorf(fy);
    z0 = (int)floorf(fz);
}

__device__ __forceinline__ int bucket_of(int x0, int y0, int z0) {
    const int bx = min(max(x0, 0), GD - 1) >> 2;
    const int by = min(max(y0, 0), GD - 1) >> 2;
    const int bz = min(max(z0, 0), GD - 1) >> 2;
    return (bz << 10) | (by << 5) | bx;
}

// ---------------- histogram over buckets ----------------
__global__ __launch_bounds__(256) void hist_k(
    const float* __restrict__ x, unsigned* __restrict__ hist, int npts) {
    const int n = blockIdx.x * 256 + threadIdx.x;
    if (n >= npts) return;
    int x0, y0, z0;
    cell_of(x[3 * n], x[3 * n + 1], x[3 * n + 2], x0, y0, z0);
    atomicAdd(&hist[bucket_of(x0, y0, z0)], 1u);
}

// ---------------- exclusive scan of 32768 counts (one block) ------------
__global__ __launch_bounds__(1024) void scan_k(
    const unsigned* __restrict__ hist, unsigned* __restrict__ cursor) {
    __shared__ unsigned part[1024];
    const int t = threadIdx.x;
    unsigned v[32];
    unsigned s = 0;
#pragma unroll
    for (int i = 0; i < 32; ++i) {
        v[i] = hist[t * 32 + i];
        s += v[i];
    }
    part[t] = s;
    __syncthreads();
    for (int off = 1; off < 1024; off <<= 1) {
        const unsigned a = (t >= off) ? part[t - off] : 0u;
        __syncthreads();
        part[t] += a;
        __syncthreads();
    }
    unsigned run = part[t] - s;  // exclusive prefix
#pragma unroll
    for (int i = 0; i < 32; ++i) {
        cursor[t * 32 + i] = run;
        run += v[i];
    }
}

// ---------------- scatter points into sorted record array ----------------
__global__ __launch_bounds__(256) void scatter_k(
    const float* __restrict__ x, unsigned* __restrict__ cursor,
    vf4* __restrict__ rec, int npts) {
    const int n = blockIdx.x * 256 + threadIdx.x;
    if (n >= npts) return;
    const float px = x[3 * n], py = x[3 * n + 1], pz = x[3 * n + 2];
    int x0, y0, z0;
    cell_of(px, py, pz, x0, y0, z0);
    const unsigned pos = atomicAdd(&cursor[bucket_of(x0, y0, z0)], 1u);
    vf4 r;
    r.x = px; r.y = py; r.z = pz; r.w = __int_as_float(n);
    rec[pos] = r;
}

// ---------------- gather: 8 threads per sorted point ----------------
__global__ __launch_bounds__(256) void trilerp_sorted(
    const vf4* __restrict__ rec, const float* __restrict__ ft,
    float* __restrict__ out, int npts, int nblk_logical) {
    // XCD swizzle: consecutive logical blocks -> same XCD (blockIdx % 8)
    const int P = (nblk_logical + 7) / 8;
    const int logical = (blockIdx.x & 7) * P + (blockIdx.x >> 3);
    if (logical >= nblk_logical) return;
    const int tid = logical * 256 + threadIdx.x;
    const int slot = tid >> 3;
    if (slot >= npts) return;
    const int j = tid & 7;  // channel quad

    const vf4 r = rec[slot];
    const int n = __float_as_int(r.w);

    const float cx = 2.0f * (r.x - PLO) / (PHI - PLO) - 1.0f;
    const float cy = 2.0f * (r.y - PLO) / (PHI - PLO) - 1.0f;
    const float cz = 2.0f * (r.z - PLO) / (PHI - PLO) - 1.0f;
    const float fx = ((cx + 1.0f) * GD - 1.0f) * 0.5f;
    const float fy = ((cy + 1.0f) * GD - 1.0f) * 0.5f;
    const float fz = ((cz + 1.0f) * GD - 1.0f) * 0.5f;
    const float x0f = floorf(fx), y0f = floorf(fy), z0f = floorf(fz);
    const float wx = fx - x0f, wy = fy - y0f, wz = fz - z0f;
    const int x0 = (int)x0f, y0 = (int)y0f, z0 = (int)z0f;

    vf4 acc = (vf4)0.f;
#pragma unroll
    for (int dz = 0; dz < 2; ++dz) {
#pragma unroll
        for (int dy = 0; dy < 2; ++dy) {
#pragma unroll
            for (int dx = 0; dx < 2; ++dx) {
                const int xi = x0 + dx, yi = y0 + dy, zi = z0 + dz;
                const bool valid = ((unsigned)xi < (unsigned)GD) &
                                   ((unsigned)yi < (unsigned)GD) &
                                   ((unsigned)zi < (unsigned)GD);
                float w = (dx ? wx : 1.0f - wx) * (dy ? wy : 1.0f - wy) *
                          (dz ? wz : 1.0f - wz);
                w = valid ? w : 0.0f;
                const int xc = min(max(xi, 0), GD - 1);
                const int yc = min(max(yi, 0), GD - 1);
                const int zc = min(max(zi, 0), GD - 1);
                const size_t idx = (size_t)(zc * GD + yc) * GD + xc;
                const vf4 v =
                    *reinterpret_cast<const vf4*>(ft + idx * FD + j * 4);
                acc.x = fmaf(v.x, w, acc.x);
                acc.y = fmaf(v.y, w, acc.y);
                acc.z = fmaf(v.z, w, acc.z);
                acc.w = fmaf(v.w, w, acc.w);
            }
        }
    }
    __builtin_nontemporal_store(
        acc, reinterpret_cast<vf4*>(out + (size_t)n * FD + j * 4));
}

// ---------------- fallback: unsorted gather on transposed ft --------------
__global__ __launch_bounds__(256) void trilerp(
    const float* __restrict__ x, const float* __restrict__ ft,
    float* __restrict__ out, int npts) {
    const int tid = blockIdx.x * 256 + threadIdx.x;
    const int n = tid >> 3;
    if (n >= npts) return;
    const int j = tid & 7;
    const float px = x[3 * n], py = x[3 * n + 1], pz = x[3 * n + 2];
    const float cx = 2.0f * (px - PLO) / (PHI - PLO) - 1.0f;
    const float cy = 2.0f * (py - PLO) / (PHI - PLO) - 1.0f;
    const float cz = 2.0f * (pz - PLO) / (PHI - PLO) - 1.0f;
    const float fx = ((cx + 1.0f) * GD - 1.0f) * 0.5f;
    const float fy = ((cy + 1.0f) * GD - 1.0f) * 0.5f;
    const float fz = ((cz + 1.0f) * GD - 1.0f) * 0.5f;
    const float x0f = floorf(fx), y0f = floorf(fy), z0f = floorf(fz);
    const float wx = fx - x0f, wy = fy - y0f, wz = fz - z0f;
    const int x0 = (int)x0f, y0 = (int)y0f, z0 = (int)z0f;
    vf4 acc = (vf4)0.f;
#pragma unroll
    for (int dz = 0; dz < 2; ++dz)
#pragma unroll
        for (int dy = 0; dy < 2; ++dy)
#pragma unroll
            for (int dx = 0; dx < 2; ++dx) {
                const int xi = x0 + dx, yi = y0 + dy, zi = z0 + dz;
                const bool valid = ((unsigned)xi < (unsigned)GD) &
                                   ((unsigned)yi < (unsigned)GD) &
                                   ((unsigned)zi < (unsigned)GD);
                float w = (dx ? wx : 1.0f - wx) * (dy ? wy : 1.0f - wy) *
                          (dz ? wz : 1.0f - wz);
                w = valid ? w : 0.0f;
                const int xc = min(max(xi, 0), GD - 1);
                const int yc = min(max(yi, 0), GD - 1);
                const int zc = min(max(zi, 0), GD - 1);
                const size_t idx = (size_t)(zc * GD + yc) * GD + xc;
                const vf4 v =
                    *reinterpret_cast<const vf4*>(ft + idx * FD + j * 4);
                acc.x = fmaf(v.x, w, acc.x);
                acc.y = fmaf(v.y, w, acc.y);
                acc.z = fmaf(v.z, w, acc.z);
                acc.w = fmaf(v.w, w, acc.w);
            }
    __builtin_nontemporal_store(
        acc, reinterpret_cast<vf4*>(out + (size_t)n * FD + j * 4));
}

extern "C" void kernel_launch(void* const* d_in, const int* in_sizes, int n_in,
                              void* d_out, int out_size, void* d_ws, size_t ws_size,
                              hipStream_t stream) {
    const float* x    = (const float*)d_in[0];
    const float* feat = (const float*)d_in[1];
    float*       out  = (float*)d_out;
    const int npts = in_sizes[0] / 3;

    const size_t ft_bytes   = (size_t)SPATIAL * FD * sizeof(float);  // 256 MiB
    const size_t hist_off   = ft_bytes;
    const size_t cursor_off = hist_off + NBUCKET * sizeof(unsigned);
    const size_t rec_off    = cursor_off + NBUCKET * sizeof(unsigned);
    const size_t need_sort  = rec_off + (size_t)npts * sizeof(vf4);

    const int nblk_logical = (npts * 8 + 255) / 256;
    const int pblocks      = (npts + 255) / 256;

    if (ws_size >= need_sort) {
        float*    ft     = (float*)d_ws;
        unsigned* hist   = (unsigned*)((char*)d_ws + hist_off);
        unsigned* cursor = (unsigned*)((char*)d_ws + cursor_off);
        vf4*      rec    = (vf4*)((char*)d_ws + rec_off);

        (void)hipMemsetAsync(hist, 0, NBUCKET * sizeof(unsigned), stream);
        transpose_feat_v4<<<(int)(SPATIAL / 64), 256, 0, stream>>>(feat, ft);
        hist_k<<<pblocks, 256, 0, stream>>>(x, hist, npts);
        scan_k<<<1, 1024, 0, stream>>>(hist, cursor);
        scatter_k<<<pblocks, 256, 0, stream>>>(x, cursor, rec, npts);
        const int P = (nblk_logical + 7) / 8;
        trilerp_sorted<<<8 * P, 256, 0, stream>>>(rec, ft, out, npts, nblk_logical);
    } else if (ws_size >= ft_bytes) {
        float* ft = (float*)d_ws;
        transpose_feat_v4<<<(int)(SPATIAL / 64), 256, 0, stream>>>(feat, ft);
        trilerp<<<nblk_logical, 256, 0, stream>>>(x, ft, out, npts);
    }
}